// Round 1
// 5459.776 us; speedup vs baseline: 1.6375x; 1.6375x over previous
//
#include <hip/hip_runtime.h>
#include <hip/hip_bf16.h>
#include <math.h>

#define BATCH 4
#define SEQ   2048
#define DIM   1024
#define MROWS (SEQ*BATCH)          // 8192
#define BIGN  ((size_t)MROWS*DIM)  // 8388608 floats per buffer

// ---------------- chunked scan for r_t = dec*r + k*v,  ret = q*r --------------
__global__ __launch_bounds__(256) void scan_a(const float* __restrict__ K,
    const float* __restrict__ V, const float* __restrict__ dec_p,
    float* __restrict__ E)
{
  int id  = blockIdx.x*256 + threadIdx.x;   // 0..262143
  int c   = id >> 12;
  int rem = id & 4095;
  int b   = rem >> 10;
  int dc  = rem & 1023;
  float dec = dec_p[dc >> 6];
  size_t base = ((size_t)b*SEQ + (size_t)c*32)*DIM + dc;
  float r = 0.f;
  #pragma unroll 4
  for (int i = 0; i < 32; ++i) {
    float kv = K[base + (size_t)i*DIM] * V[base + (size_t)i*DIM];
    r = fmaf(dec, r, kv);
  }
  E[(size_t)c*4096 + rem] = r;
}

__global__ __launch_bounds__(256) void scan_b(const float* __restrict__ E,
    const float* __restrict__ dec_p, float* __restrict__ carry)
{
  int id = blockIdx.x*256 + threadIdx.x;    // 0..4095
  int dc = id & 1023;
  float dec = dec_p[dc >> 6];
  float d2 = dec*dec, d4 = d2*d2, d8 = d4*d4, d16 = d8*d8, d32 = d16*d16;
  float r = 0.f;
  #pragma unroll 1
  for (int c = 0; c < 64; ++c) {
    carry[(size_t)c*4096 + id] = r;
    r = fmaf(d32, r, E[(size_t)c*4096 + id]);
  }
}

__global__ __launch_bounds__(256) void scan_c(const float* __restrict__ Q,
    const float* __restrict__ K, const float* __restrict__ V,
    const float* __restrict__ dec_p, const float* __restrict__ carry,
    float* __restrict__ ret)
{
  int id  = blockIdx.x*256 + threadIdx.x;
  int c   = id >> 12;
  int rem = id & 4095;
  int b   = rem >> 10;
  int dc  = rem & 1023;
  float dec = dec_p[dc >> 6];
  size_t base = ((size_t)b*SEQ + (size_t)c*32)*DIM + dc;
  float r = carry[(size_t)c*4096 + rem];
  #pragma unroll 1
  for (int i = 0; i < 32; ++i) {
    int t = c*32 + i;
    float kv = K[base + (size_t)i*DIM] * V[base + (size_t)i*DIM];
    r = fmaf(dec, r, kv);
    ret[((size_t)t*BATCH + b)*DIM + dc] = Q[base + (size_t)i*DIM] * r;
  }
}

// ---------------- fp32 tiled GEMM: C[m,n] = sum_k X[m,k]*W[n,k] (+bias) -------
// MODE 0: C = XW^T + bias
// MODE 1: g = sigmoid(XW^T + bias) -> C;  u_out = (1-g)*inp
// MODE 2: C += XW^T
// MODE 3: outf[b,t,n] = XW^T + bias   (m = t*4+b scatter), float32 output
// MODE 4: C = XW^T
#define GM 64
#define GN 64
#define GK 32
#define LDA 68

template<int MODE>
__global__ __launch_bounds__(256) void gemm_k(
    const float* __restrict__ X, const float* __restrict__ W,
    const float* __restrict__ bias, float* __restrict__ C,
    const float* __restrict__ inp, float* __restrict__ u_out,
    float* __restrict__ outf)
{
  __shared__ float Xs[GK][LDA];
  __shared__ float Ws[GK][LDA];
  const int tid = threadIdx.x;
  const int m0 = blockIdx.y * GM;
  const int n0 = blockIdx.x * GN;
  const int tx = tid & 15, ty = tid >> 4;
  float acc[4][4] = {};
  #pragma unroll 1
  for (int kb = 0; kb < DIM; kb += GK) {
    #pragma unroll
    for (int h = 0; h < 2; ++h) {
      int idx = tid + h*256;
      int row = idx >> 3;        // 0..63
      int kc  = (idx & 7) << 2;  // 0,4,...,28
      float4 xv = *(const float4*)(X + (size_t)(m0+row)*DIM + kb + kc);
      Xs[kc+0][row] = xv.x; Xs[kc+1][row] = xv.y;
      Xs[kc+2][row] = xv.z; Xs[kc+3][row] = xv.w;
      float4 wv = *(const float4*)(W + (size_t)(n0+row)*DIM + kb + kc);
      Ws[kc+0][row] = wv.x; Ws[kc+1][row] = wv.y;
      Ws[kc+2][row] = wv.z; Ws[kc+3][row] = wv.w;
    }
    __syncthreads();
    #pragma unroll
    for (int kk = 0; kk < GK; ++kk) {
      float4 a = *(const float4*)&Xs[kk][ty << 2];
      float4 w = *(const float4*)&Ws[kk][tx << 2];
      float av[4] = {a.x, a.y, a.z, a.w};
      float wv[4] = {w.x, w.y, w.z, w.w};
      #pragma unroll
      for (int i = 0; i < 4; ++i)
        #pragma unroll
        for (int j = 0; j < 4; ++j)
          acc[i][j] = fmaf(av[i], wv[j], acc[i][j]);
    }
    __syncthreads();
  }
  float bj[4];
  #pragma unroll
  for (int j = 0; j < 4; ++j)
    bj[j] = (MODE == 0 || MODE == 1 || MODE == 3) ? bias[n0 + (tx<<2) + j] : 0.f;
  #pragma unroll
  for (int i = 0; i < 4; ++i) {
    int m = m0 + (ty<<2) + i;
    #pragma unroll
    for (int j = 0; j < 4; ++j) {
      int n = n0 + (tx<<2) + j;
      size_t off = (size_t)m*DIM + n;
      float vv = acc[i][j] + bj[j];
      if (MODE == 2) vv += C[off];
      if (MODE == 1) {
        float gv = 1.f/(1.f + expf(-vv));
        C[off] = gv;
        u_out[off] = (1.f - gv) * inp[off];
      } else if (MODE == 3) {
        outf[((size_t)(m & 3)*SEQ + (size_t)(m >> 2))*DIM + n] = vv;
      } else {
        C[off] = vv;
      }
    }
  }
}

// ---------------- sequential recurrence: s_t = tanh((g_t*s_{t-1})@A^T + d_t) --
// 4 independent batch chains. Per batch: 16 blocks x 512 threads, each block
// owns 64 rows of A in registers (8 lanes/row, k split 8x128).
//
// Sync redesign (flag-in-data ring):
//   Each produced s element is published as one 8-byte atomic word
//   {f32 value, u32 tag = t+1} into a 2-slot ring sf[2][B][1024] (64 KB,
//   IC-resident). Consumers poll the ring words DIRECTLY: when the tag is
//   visible, the value is in the same 8B word -> no separate flag line, no
//   release drain before publishing, no second fetch after discovery.
//   This removes 2 of the ~5 serialized fabric round trips per step that
//   made the old counter-based barrier cost 3.65 us/step.
//   Ring reuse (R=2) is safe: observing all step-(t-1) tags proves every
//   block already loaded step-(t-2) data, so slot t&1 may be overwritten.
//   Tags are monotone (t+1), so no per-step reset; one 64 KB memset per
//   launch clears cross-launch staleness.
#define RBLK 64

__global__ __launch_bounds__(512, 2) void recur_k(
    const float* __restrict__ A, const float* __restrict__ g,
    const float* __restrict__ dpre, float* __restrict__ s,
    unsigned long long* __restrict__ sf)
{
  __shared__ __align__(16) float xs[8*132 + 4];   // 4240 B
  const int tid = threadIdx.x;
  const int w   = tid >> 6;                 // wave 0..7
  const int ln  = tid & 63;
  const int b   = blockIdx.x >> 4;          // batch 0..3
  const int blk = blockIdx.x & 15;          // block within batch
  const int row = blk*64 + w*8 + (ln >> 3); // global row 0..1023
  const int ks  = ln & 7;                   // k-slice (128 floats)

  const size_t slotstride = (size_t)BATCH*DIM;     // ulls per ring slot
  unsigned long long* sfb = sf + (size_t)b*DIM;    // this batch, slot 0

  // A fragment: (row, k in [ks*128, ks*128+128))
  float4 areg[32];
  #pragma unroll
  for (int j = 0; j < 32; ++j)
    areg[j] = *(const float4*)(A + (size_t)row*DIM + ks*128 + 4*j);

  // x-staging slot for this thread: floats [2*tid, 2*tid+1] of x
  const int xoff = (tid >> 6)*132 + ((2*tid) & 127);

  #pragma unroll 1
  for (int t = 0; t < SEQ; ++t) {
    // prefetches (flag-independent -> issue before the spin)
    float2 gv = *(const float2*)(g + ((size_t)t*4 + b)*DIM + 2*tid);
    float dval = (ks == 0) ? dpre[((size_t)t*4 + b)*DIM + row] : 0.f;

    float acc0 = 0.f, acc1 = 0.f, acc2 = 0.f, acc3 = 0.f;
    if (t > 0) {
      // poll the two flagged data words this thread stages (x[2t], x[2t+1])
      unsigned long long* p0 = sfb + (size_t)((t-1)&1)*slotstride + 2*tid;
      const unsigned want = (unsigned)t;    // producer at t-1 wrote tag t
      union { unsigned long long u; unsigned ui[2]; float f[2]; } a0, a1;
      int guard = 0;
      for (;;) {
        a0.u = __hip_atomic_load(p0,     __ATOMIC_RELAXED,
                                 __HIP_MEMORY_SCOPE_AGENT);
        a1.u = __hip_atomic_load(p0 + 1, __ATOMIC_RELAXED,
                                 __HIP_MEMORY_SCOPE_AGENT);
        if ((a0.ui[1] == want && a1.ui[1] == want) || ++guard > (1 << 25))
          break;
      }

      // stage x = g * s[t-1][b] : one float2 per thread (4KB/block total)
      *(float2*)(xs + xoff) = make_float2(gv.x * a0.f[0], gv.y * a1.f[0]);
      __syncthreads();

      // matvec: this lane covers k-slice ks of its row
      const float* xb = xs + ks*132;
      #pragma unroll
      for (int j = 0; j < 32; j += 4) {
        float4 x0 = *(const float4*)(xb + 4*j);
        float4 x1 = *(const float4*)(xb + 4*j + 4);
        float4 x2 = *(const float4*)(xb + 4*j + 8);
        float4 x3 = *(const float4*)(xb + 4*j + 12);
        acc0 = fmaf(areg[j+0].x, x0.x, fmaf(areg[j+0].y, x0.y,
               fmaf(areg[j+0].z, x0.z, fmaf(areg[j+0].w, x0.w, acc0))));
        acc1 = fmaf(areg[j+1].x, x1.x, fmaf(areg[j+1].y, x1.y,
               fmaf(areg[j+1].z, x1.z, fmaf(areg[j+1].w, x1.w, acc1))));
        acc2 = fmaf(areg[j+2].x, x2.x, fmaf(areg[j+2].y, x2.y,
               fmaf(areg[j+2].z, x2.z, fmaf(areg[j+2].w, x2.w, acc2))));
        acc3 = fmaf(areg[j+3].x, x3.x, fmaf(areg[j+3].y, x3.y,
               fmaf(areg[j+3].z, x3.z, fmaf(areg[j+3].w, x3.w, acc3))));
      }
    }
    float sum = (acc0 + acc1) + (acc2 + acc3);
    // reduce over the 8 k-slice lanes of this row
    sum += __shfl_xor(sum, 1, 64);
    sum += __shfl_xor(sum, 2, 64);
    sum += __shfl_xor(sum, 4, 64);
    if (ks == 0) {
      float val = tanhf(sum + dval);
      // plain store for the later output GEMM (kernel-boundary visibility)
      s[((size_t)t*4 + b)*DIM + row] = val;
      // flagged publish: value+tag in ONE 8B atomic word (self-ordering)
      union { unsigned long long u; unsigned ui[2]; float f[2]; } pk;
      pk.f[0] = val; pk.ui[1] = (unsigned)(t + 1);
      __hip_atomic_store(sfb + (size_t)(t & 1)*slotstride + row, pk.u,
                         __ATOMIC_RELAXED, __HIP_MEMORY_SCOPE_AGENT);
    }
    __syncthreads();   // protects xs reuse across iterations
  }
}

// ------------------------------------------------------------------------------
extern "C" void kernel_launch(void* const* d_in, const int* in_sizes, int n_in,
                              void* d_out, int out_size, void* d_ws, size_t ws_size,
                              hipStream_t stream)
{
  (void)in_sizes; (void)n_in; (void)out_size;
  const float* q   = (const float*)d_in[0];
  const float* k   = (const float*)d_in[1];
  const float* v   = (const float*)d_in[2];
  const float* Wi  = (const float*)d_in[3];
  const float* bi  = (const float*)d_in[4];
  const float* Wg  = (const float*)d_in[5];
  const float* bg  = (const float*)d_in[6];
  const float* A   = (const float*)d_in[7];
  const float* Bm  = (const float*)d_in[8];
  const float* Wo  = (const float*)d_in[9];
  const float* bo  = (const float*)d_in[10];
  const float* dec = (const float*)d_in[11];

  const size_t sf_bytes = (size_t)2*BATCH*DIM*sizeof(unsigned long long); // 64KB
  size_t need = (4*BIGN + 2*(size_t)64*4096)*sizeof(float) + sf_bytes;
  if (ws_size < need) return;

  float* b0 = (float*)d_ws;          // ret -> u -> s
  float* b1 = b0 + BIGN;             // inp
  float* b2 = b1 + BIGN;             // g
  float* b3 = b2 + BIGN;             // d  (pre-activation constant)
  float* E     = b3 + BIGN;
  float* carry = E + (size_t)64*4096;
  unsigned long long* sf = (unsigned long long*)(carry + (size_t)64*4096);
  float* outp  = (float*)d_out;

  hipMemsetAsync(sf, 0, sf_bytes, stream);

  scan_a<<<1024, 256, 0, stream>>>(k, v, dec, E);
  scan_b<<<16,   256, 0, stream>>>(E, dec, carry);
  scan_c<<<1024, 256, 0, stream>>>(q, k, v, dec, carry, b0);

  dim3 gg(DIM/GN, MROWS/GM);
  gemm_k<0><<<gg, 256, 0, stream>>>(b0, Wi, bi, b1, nullptr, nullptr, nullptr); // inp
  gemm_k<1><<<gg, 256, 0, stream>>>(b1, Wg, bg, b2, b1, b0, nullptr);           // g, u
  gemm_k<4><<<gg, 256, 0, stream>>>(b0, A,  nullptr, b3, nullptr, nullptr, nullptr); // d  = u@A^T
  gemm_k<2><<<gg, 256, 0, stream>>>(b1, Bm, nullptr, b3, nullptr, nullptr, nullptr); // d += inp@Bm^T

  recur_k<<<RBLK, 512, 0, stream>>>(A, b2, b3, b0, sf);                         // s

  gemm_k<3><<<gg, 256, 0, stream>>>(b0, Wo, bo, nullptr, nullptr, nullptr, outp); // out
}

// Round 2
// 5078.285 us; speedup vs baseline: 1.7606x; 1.0751x over previous
//
#include <hip/hip_runtime.h>
#include <hip/hip_bf16.h>
#include <math.h>

#define BATCH 4
#define SEQ   2048
#define DIM   1024
#define MROWS (SEQ*BATCH)          // 8192
#define BIGN  ((size_t)MROWS*DIM)  // 8388608 floats per buffer

typedef float v2f __attribute__((ext_vector_type(2)));

// ---------------- chunked scan for r_t = dec*r + k*v,  ret = q*r --------------
__global__ __launch_bounds__(256) void scan_a(const float* __restrict__ K,
    const float* __restrict__ V, const float* __restrict__ dec_p,
    float* __restrict__ E)
{
  int id  = blockIdx.x*256 + threadIdx.x;   // 0..262143
  int c   = id >> 12;
  int rem = id & 4095;
  int b   = rem >> 10;
  int dc  = rem & 1023;
  float dec = dec_p[dc >> 6];
  size_t base = ((size_t)b*SEQ + (size_t)c*32)*DIM + dc;
  float r = 0.f;
  #pragma unroll 4
  for (int i = 0; i < 32; ++i) {
    float kv = K[base + (size_t)i*DIM] * V[base + (size_t)i*DIM];
    r = fmaf(dec, r, kv);
  }
  E[(size_t)c*4096 + rem] = r;
}

__global__ __launch_bounds__(256) void scan_b(const float* __restrict__ E,
    const float* __restrict__ dec_p, float* __restrict__ carry)
{
  int id = blockIdx.x*256 + threadIdx.x;    // 0..4095
  int dc = id & 1023;
  float dec = dec_p[dc >> 6];
  float d2 = dec*dec, d4 = d2*d2, d8 = d4*d4, d16 = d8*d8, d32 = d16*d16;
  float r = 0.f;
  #pragma unroll 1
  for (int c = 0; c < 64; ++c) {
    carry[(size_t)c*4096 + id] = r;
    r = fmaf(d32, r, E[(size_t)c*4096 + id]);
  }
}

__global__ __launch_bounds__(256) void scan_c(const float* __restrict__ Q,
    const float* __restrict__ K, const float* __restrict__ V,
    const float* __restrict__ dec_p, const float* __restrict__ carry,
    float* __restrict__ ret)
{
  int id  = blockIdx.x*256 + threadIdx.x;
  int c   = id >> 12;
  int rem = id & 4095;
  int b   = rem >> 10;
  int dc  = rem & 1023;
  float dec = dec_p[dc >> 6];
  size_t base = ((size_t)b*SEQ + (size_t)c*32)*DIM + dc;
  float r = carry[(size_t)c*4096 + rem];
  #pragma unroll 1
  for (int i = 0; i < 32; ++i) {
    int t = c*32 + i;
    float kv = K[base + (size_t)i*DIM] * V[base + (size_t)i*DIM];
    r = fmaf(dec, r, kv);
    ret[((size_t)t*BATCH + b)*DIM + dc] = Q[base + (size_t)i*DIM] * r;
  }
}

// ---------------- fp32 tiled GEMM: C[m,n] = sum_k X[m,k]*W[n,k] (+bias) -------
// MODE 0: C = XW^T + bias
// MODE 1: g = sigmoid(XW^T + bias) -> C;  u_out = (1-g)*inp
// MODE 2: C += XW^T
// MODE 3: outf[b,t,n] = XW^T + bias   (m = t*4+b scatter), float32 output
// MODE 4: C = XW^T
// Inner product uses v2f packed math -> v_pk_fma_f32 (fp32 peak 157 TF is the
// PACKED rate; scalar fma runs at half). 8 pk-fma per k instead of 16 fma.
#define GM 64
#define GN 64
#define GK 32
#define LDA 68

template<int MODE>
__global__ __launch_bounds__(256) void gemm_k(
    const float* __restrict__ X, const float* __restrict__ W,
    const float* __restrict__ bias, float* __restrict__ C,
    const float* __restrict__ inp, float* __restrict__ u_out,
    float* __restrict__ outf)
{
  __shared__ float Xs[GK][LDA];
  __shared__ float Ws[GK][LDA];
  const int tid = threadIdx.x;
  const int m0 = blockIdx.y * GM;
  const int n0 = blockIdx.x * GN;
  const int tx = tid & 15, ty = tid >> 4;
  v2f acc[4][2] = {};
  #pragma unroll 1
  for (int kb = 0; kb < DIM; kb += GK) {
    #pragma unroll
    for (int h = 0; h < 2; ++h) {
      int idx = tid + h*256;
      int row = idx >> 3;        // 0..63
      int kc  = (idx & 7) << 2;  // 0,4,...,28
      float4 xv = *(const float4*)(X + (size_t)(m0+row)*DIM + kb + kc);
      Xs[kc+0][row] = xv.x; Xs[kc+1][row] = xv.y;
      Xs[kc+2][row] = xv.z; Xs[kc+3][row] = xv.w;
      float4 wv = *(const float4*)(W + (size_t)(n0+row)*DIM + kb + kc);
      Ws[kc+0][row] = wv.x; Ws[kc+1][row] = wv.y;
      Ws[kc+2][row] = wv.z; Ws[kc+3][row] = wv.w;
    }
    __syncthreads();
    #pragma unroll
    for (int kk = 0; kk < GK; ++kk) {
      float4 a = *(const float4*)&Xs[kk][ty << 2];
      float4 w = *(const float4*)&Ws[kk][tx << 2];
      v2f w0 = {w.x, w.y};
      v2f w1 = {w.z, w.w};
      float av[4] = {a.x, a.y, a.z, a.w};
      #pragma unroll
      for (int i = 0; i < 4; ++i) {
        v2f ab = {av[i], av[i]};
        acc[i][0] = __builtin_elementwise_fma(ab, w0, acc[i][0]);
        acc[i][1] = __builtin_elementwise_fma(ab, w1, acc[i][1]);
      }
    }
    __syncthreads();
  }
  float bj[4];
  #pragma unroll
  for (int j = 0; j < 4; ++j)
    bj[j] = (MODE == 0 || MODE == 1 || MODE == 3) ? bias[n0 + (tx<<2) + j] : 0.f;
  #pragma unroll
  for (int i = 0; i < 4; ++i) {
    int m = m0 + (ty<<2) + i;
    #pragma unroll
    for (int j = 0; j < 4; ++j) {
      int n = n0 + (tx<<2) + j;
      size_t off = (size_t)m*DIM + n;
      float vv = acc[i][j >> 1][j & 1] + bj[j];
      if (MODE == 2) vv += C[off];
      if (MODE == 1) {
        float gv = 1.f/(1.f + expf(-vv));
        C[off] = gv;
        u_out[off] = (1.f - gv) * inp[off];
      } else if (MODE == 3) {
        outf[((size_t)(m & 3)*SEQ + (size_t)(m >> 2))*DIM + n] = vv;
      } else {
        C[off] = vv;
      }
    }
  }
}

// ---------------- sequential recurrence: s_t = tanh((g_t*s_{t-1})@A^T + d_t) --
// 4 independent batch chains. Per batch: 16 blocks x 512 threads, each block
// owns 64 rows of A in registers (8 lanes/row, k split 8x128).
//
// Sync: flag-in-data 2-slot ring sf[2][B][1024] of {f32 val, u32 tag=t+1}
// 8B words, polled directly with relaxed agent loads (see ring-safety proof
// in the r1 comment: observing all step-(t-1) tags proves every block has
// consumed step-(t-2), so slot t&1 is reusable).
//
// This round:
//  - RAW barriers: the in-loop __syncthreads() drained vmcnt(0), i.e. waited
//    for the agent-scope publish store's ACK from the coherence point
//    (~500-1000 cyc) before the block could start the next poll. Stage
//    barrier now = s_waitcnt lgkmcnt(0) + s_barrier (only the LDS writes
//    must be visible); end barrier = bare s_barrier (every wave's ds_reads
//    were consumed by its FMAs before arrival -> no wait needed; the
//    publish store needs no ack before looping).
//  - Packed matvec: v2f + __builtin_elementwise_fma -> v_pk_fma_f32,
//    64 pk ops instead of 128 scalar fma (halves VALU issue on the
//    critical path). Bitwise-identical rounding (IEEE fma per lane).
#define RBLK 64

__global__ __launch_bounds__(512, 2) void recur_k(
    const float* __restrict__ A, const float* __restrict__ g,
    const float* __restrict__ dpre, float* __restrict__ s,
    unsigned long long* __restrict__ sf)
{
  __shared__ __align__(16) float xs[8*132 + 4];   // 4240 B
  const int tid = threadIdx.x;
  const int w   = tid >> 6;                 // wave 0..7
  const int ln  = tid & 63;
  const int b   = blockIdx.x >> 4;          // batch 0..3
  const int blk = blockIdx.x & 15;          // block within batch
  const int row = blk*64 + w*8 + (ln >> 3); // global row 0..1023
  const int ks  = ln & 7;                   // k-slice (128 floats)

  const size_t slotstride = (size_t)BATCH*DIM;     // ulls per ring slot
  unsigned long long* sfb = sf + (size_t)b*DIM;    // this batch, slot 0

  // A fragment: (row, k in [ks*128, ks*128+128))
  float4 areg[32];
  #pragma unroll
  for (int j = 0; j < 32; ++j)
    areg[j] = *(const float4*)(A + (size_t)row*DIM + ks*128 + 4*j);
  const v2f* a2 = reinterpret_cast<const v2f*>(areg);   // a2[2j],a2[2j+1]

  // x-staging slot for this thread: floats [2*tid, 2*tid+1] of x
  const int xoff = (tid >> 6)*132 + ((2*tid) & 127);

  #pragma unroll 1
  for (int t = 0; t < SEQ; ++t) {
    // prefetches (flag-independent -> issue before the spin)
    float2 gv = *(const float2*)(g + ((size_t)t*4 + b)*DIM + 2*tid);
    float dval = (ks == 0) ? dpre[((size_t)t*4 + b)*DIM + row] : 0.f;

    v2f acc0 = {0.f, 0.f}, acc1 = {0.f, 0.f};
    v2f acc2 = {0.f, 0.f}, acc3 = {0.f, 0.f};
    if (t > 0) {
      // poll the two flagged data words this thread stages (x[2t], x[2t+1])
      unsigned long long* p0 = sfb + (size_t)((t-1)&1)*slotstride + 2*tid;
      const unsigned want = (unsigned)t;    // producer at t-1 wrote tag t
      union { unsigned long long u; unsigned ui[2]; float f[2]; } a0, a1;
      int guard = 0;
      for (;;) {
        a0.u = __hip_atomic_load(p0,     __ATOMIC_RELAXED,
                                 __HIP_MEMORY_SCOPE_AGENT);
        a1.u = __hip_atomic_load(p0 + 1, __ATOMIC_RELAXED,
                                 __HIP_MEMORY_SCOPE_AGENT);
        if ((a0.ui[1] == want && a1.ui[1] == want) || ++guard > (1 << 25))
          break;
      }

      // stage x = g * s[t-1][b] : one float2 per thread (4KB/block total)
      *(float2*)(xs + xoff) = make_float2(gv.x * a0.f[0], gv.y * a1.f[0]);
      // stage barrier: only LDS writes must be block-visible (no vmcnt drain)
      asm volatile("s_waitcnt lgkmcnt(0)\n\ts_barrier" ::: "memory");

      // matvec: this lane covers k-slice ks of its row (packed fp32)
      const float* xb = xs + ks*132;
      #pragma unroll
      for (int j = 0; j < 32; j += 4) {
        float4 x0 = *(const float4*)(xb + 4*j);
        float4 x1 = *(const float4*)(xb + 4*j + 4);
        float4 x2 = *(const float4*)(xb + 4*j + 8);
        float4 x3 = *(const float4*)(xb + 4*j + 12);
        v2f x0l = {x0.x, x0.y}, x0h = {x0.z, x0.w};
        v2f x1l = {x1.x, x1.y}, x1h = {x1.z, x1.w};
        v2f x2l = {x2.x, x2.y}, x2h = {x2.z, x2.w};
        v2f x3l = {x3.x, x3.y}, x3h = {x3.z, x3.w};
        acc0 = __builtin_elementwise_fma(a2[2*j+0], x0l, acc0);
        acc0 = __builtin_elementwise_fma(a2[2*j+1], x0h, acc0);
        acc1 = __builtin_elementwise_fma(a2[2*j+2], x1l, acc1);
        acc1 = __builtin_elementwise_fma(a2[2*j+3], x1h, acc1);
        acc2 = __builtin_elementwise_fma(a2[2*j+4], x2l, acc2);
        acc2 = __builtin_elementwise_fma(a2[2*j+5], x2h, acc2);
        acc3 = __builtin_elementwise_fma(a2[2*j+6], x3l, acc3);
        acc3 = __builtin_elementwise_fma(a2[2*j+7], x3h, acc3);
      }
    }
    v2f accp = (acc0 + acc1) + (acc2 + acc3);
    float sum = accp.x + accp.y;
    // reduce over the 8 k-slice lanes of this row
    sum += __shfl_xor(sum, 1, 64);
    sum += __shfl_xor(sum, 2, 64);
    sum += __shfl_xor(sum, 4, 64);
    if (ks == 0) {
      float val = tanhf(sum + dval);
      // flagged publish FIRST (critical path), then the plain store for the
      // later output GEMM (kernel-boundary visibility)
      union { unsigned long long u; unsigned ui[2]; float f[2]; } pk;
      pk.f[0] = val; pk.ui[1] = (unsigned)(t + 1);
      __hip_atomic_store(sfb + (size_t)(t & 1)*slotstride + row, pk.u,
                         __ATOMIC_RELAXED, __HIP_MEMORY_SCOPE_AGENT);
      s[((size_t)t*4 + b)*DIM + row] = val;
    }
    // end barrier: bare s_barrier — no vmcnt drain (publish store needs no
    // ack; xs reads were consumed before arrival, so reuse is safe)
    asm volatile("s_barrier" ::: "memory");
  }
}

// ------------------------------------------------------------------------------
extern "C" void kernel_launch(void* const* d_in, const int* in_sizes, int n_in,
                              void* d_out, int out_size, void* d_ws, size_t ws_size,
                              hipStream_t stream)
{
  (void)in_sizes; (void)n_in; (void)out_size;
  const float* q   = (const float*)d_in[0];
  const float* k   = (const float*)d_in[1];
  const float* v   = (const float*)d_in[2];
  const float* Wi  = (const float*)d_in[3];
  const float* bi  = (const float*)d_in[4];
  const float* Wg  = (const float*)d_in[5];
  const float* bg  = (const float*)d_in[6];
  const float* A   = (const float*)d_in[7];
  const float* Bm  = (const float*)d_in[8];
  const float* Wo  = (const float*)d_in[9];
  const float* bo  = (const float*)d_in[10];
  const float* dec = (const float*)d_in[11];

  const size_t sf_bytes = (size_t)2*BATCH*DIM*sizeof(unsigned long long); // 64KB
  size_t need = (4*BIGN + 2*(size_t)64*4096)*sizeof(float) + sf_bytes;
  if (ws_size < need) return;

  float* b0 = (float*)d_ws;          // ret -> u -> s
  float* b1 = b0 + BIGN;             // inp
  float* b2 = b1 + BIGN;             // g
  float* b3 = b2 + BIGN;             // d  (pre-activation constant)
  float* E     = b3 + BIGN;
  float* carry = E + (size_t)64*4096;
  unsigned long long* sf = (unsigned long long*)(carry + (size_t)64*4096);
  float* outp  = (float*)d_out;

  hipMemsetAsync(sf, 0, sf_bytes, stream);

  scan_a<<<1024, 256, 0, stream>>>(k, v, dec, E);
  scan_b<<<16,   256, 0, stream>>>(E, dec, carry);
  scan_c<<<1024, 256, 0, stream>>>(q, k, v, dec, carry, b0);

  dim3 gg(DIM/GN, MROWS/GM);
  gemm_k<0><<<gg, 256, 0, stream>>>(b0, Wi, bi, b1, nullptr, nullptr, nullptr); // inp
  gemm_k<1><<<gg, 256, 0, stream>>>(b1, Wg, bg, b2, b1, b0, nullptr);           // g, u
  gemm_k<4><<<gg, 256, 0, stream>>>(b0, A,  nullptr, b3, nullptr, nullptr, nullptr); // d  = u@A^T
  gemm_k<2><<<gg, 256, 0, stream>>>(b1, Bm, nullptr, b3, nullptr, nullptr, nullptr); // d += inp@Bm^T

  recur_k<<<RBLK, 512, 0, stream>>>(A, b2, b3, b0, sf);                         // s

  gemm_k<3><<<gg, 256, 0, stream>>>(b0, Wo, bo, nullptr, nullptr, nullptr, outp); // out
}